// Round 1
// baseline (342.451 us; speedup 1.0000x reference)
//
#include <hip/hip_runtime.h>

#define Q 20
#define REPLICAS 64
#define RSTRIDE 21        // odd stride: co-prime with 32 banks -> at most 2-way (free) conflicts
#define BLOCK 256
#define BLOCKS_PER_ROW 32
#define L_FIXED 1000000

__global__ void zero_ws_kernel(unsigned int* __restrict__ ws, int n) {
    int i = blockIdx.x * blockDim.x + threadIdx.x;
    if (i < n) ws[i] = 0u;
}

__global__ __launch_bounds__(BLOCK) void hist_kernel(const float* __restrict__ x,
                                                     unsigned int* __restrict__ ghist,
                                                     int L) {
    __shared__ unsigned int sh[REPLICAS * RSTRIDE];
    __shared__ unsigned int fin[Q];

    for (int i = threadIdx.x; i < REPLICAS * RSTRIDE; i += BLOCK) sh[i] = 0u;
    if (threadIdx.x < Q) fin[threadIdx.x] = 0u;
    __syncthreads();

    const int row = blockIdx.x / BLOCKS_PER_ROW;
    const int cb  = blockIdx.x % BLOCKS_PER_ROW;
    const float4* __restrict__ rowp = (const float4*)(x + (long long)row * L);
    const int nvec = L >> 2;                       // L divisible by 4
    unsigned int* myrep = sh + (threadIdx.x & (REPLICAS - 1)) * RSTRIDE;

    for (int i = cb * BLOCK + threadIdx.x; i < nvec; i += BLOCKS_PER_ROW * BLOCK) {
        float4 v = rowp[i];
        int b0 = min((int)(v.x * 20.0f), Q - 1);   // x>=0 so trunc == floor, matches jnp.floor(x*20)
        int b1 = min((int)(v.y * 20.0f), Q - 1);
        int b2 = min((int)(v.z * 20.0f), Q - 1);
        int b3 = min((int)(v.w * 20.0f), Q - 1);
        atomicAdd(&myrep[b0], 1u);                 // ds_add_u32, lane-private replica -> no contention in-wave
        atomicAdd(&myrep[b1], 1u);
        atomicAdd(&myrep[b2], 1u);
        atomicAdd(&myrep[b3], 1u);
    }
    __syncthreads();

    // Reduce 64 replicas -> 20 bins: 160 active threads, q = tid/8, group g = tid%8 sums 8 replicas.
    if (threadIdx.x < Q * 8) {
        int q = threadIdx.x >> 3;
        int g = threadIdx.x & 7;
        unsigned int s = 0;
        #pragma unroll
        for (int r = 0; r < 8; ++r) s += sh[(g * 8 + r) * RSTRIDE + q];
        atomicAdd(&fin[q], s);
    }
    __syncthreads();
    if (threadIdx.x < Q) atomicAdd(&ghist[row * Q + threadIdx.x], fin[threadIdx.x]);
}

__global__ __launch_bounds__(BLOCK) void entropy_kernel(const unsigned int* __restrict__ ghist,
                                                        float* __restrict__ out,
                                                        int nbins, float invL) {
    float s = 0.0f;
    for (int i = threadIdx.x; i < nbins; i += BLOCK) {
        unsigned int c = ghist[i];
        if (c > 0u) {
            float p = (float)c * invL;
            s -= p * __log2f(p);
        }
    }
    #pragma unroll
    for (int off = 32; off > 0; off >>= 1) s += __shfl_down(s, off, 64);
    __shared__ float wsum[BLOCK / 64];
    int wid  = threadIdx.x >> 6;
    int lane = threadIdx.x & 63;
    if (lane == 0) wsum[wid] = s;
    __syncthreads();
    if (threadIdx.x == 0) {
        float t = 0.0f;
        #pragma unroll
        for (int w = 0; w < BLOCK / 64; ++w) t += wsum[w];
        out[0] = t;
    }
}

extern "C" void kernel_launch(void* const* d_in, const int* in_sizes, int n_in,
                              void* d_out, int out_size, void* d_ws, size_t ws_size,
                              hipStream_t stream) {
    const float* x = (const float*)d_in[0];
    float* out = (float*)d_out;
    unsigned int* ghist = (unsigned int*)d_ws;

    const int L = L_FIXED;
    const int B = in_sizes[0] / L;                 // 64
    const int nbins = B * Q;                       // 1280

    zero_ws_kernel<<<(nbins + BLOCK - 1) / BLOCK, BLOCK, 0, stream>>>(ghist, nbins);
    hist_kernel<<<B * BLOCKS_PER_ROW, BLOCK, 0, stream>>>(x, ghist, L);
    entropy_kernel<<<1, BLOCK, 0, stream>>>(ghist, out, nbins, 1.0f / (float)L);
}